// Round 6
// baseline (86.241 us; speedup 1.0000x reference)
//
#include <hip/hip_runtime.h>

// Varifold loss kxx + kyy - 2*kxy via mfma_f32_32x32x16_bf16, two-phase.
// R16: hybrid exp2 epilogue. Per 32x32 tile: 8 values via v_exp_f32
// (trans pipe, 16cyc/wave64 each) + 8 values via packed-math degree-5
// polynomial (floor/sub/cvt/ldexp scalar + 5x v_pk_fma_f32 per pair,
// ~26 issue-cyc/pair vs 32 for trans). Wins under BOTH bottleneck models:
// issue-block (256->232 cyc/tile) and trans-pipe-parallel (poly half runs
// on VALU concurrently with trans half). Poly = Mesa lp_build_exp2
// minimax, ~1e-7 rel on [0,1) -- below bf16-encode noise floor.
//
// R15 (kept): encode fused into vf_main. Each block re-encodes its own
// A-points (in-register) and 512 B-points (straight into LDS, lane-major)
// from raw inputs (786KB, L2-resident). Workspace = 8KB partials.
// Measured: 81.6 -> 77.7us.
// R14 (kept): grid = EXACTLY 2048 near-uniform blocks (2 x 1024 slots;
// 4 blocks/CU x 256 CU). Diagonal supertiles compute upper-triangle TILES
// only (diag tile wgt 1, off-diag 2; row r paired with 15-r -> 8 uniform
// 17-tile wave-jobs). Measured: 86.7 -> 81.6us.
//
// vf_main: lane-major fragments -> conflict-free ds_read_b128. Builtin
// MFMA (R7: raw-asm -> hazard corruption). No same-address atomics (R5).
// Per-block plain store of partial. vf_reduce: one block double-sums
// 2048 partials -> out[0].
//
// Failed levers (do not retry):
// - Fused last-block reduce via __threadfence + atomic counter (R11/R12):
//   device-scope fence emits buffer_wbl2/buffer_inv sc1 per block -> L2
//   writebacks (+21.9MB WRITE_SIZE) AND invalidation of the L2-resident
//   working set all concurrent blocks re-read -> latency-bound, vf_main
//   27->66.7us. NEVER device-fence a kernel relying on L2-resident reuse.
// - Direct-global B reads + depth-1 prefetch, no LDS (R11): cross-XCD L3
//   hits ~500-900cyc, L1 thrashes, vf_main 27->58.6us.
// - Packed-f32 epilogue (R8, ~0), 8 blocks/CU occupancy (R8, ~0), VGPR cap
//   below 128 (R9, -1.5us), SW pipeline depth 1 on MFMA (R10, +2us),
//   inline-asm MFMA (R7, corrupt).

typedef short bf16x8 __attribute__((ext_vector_type(8)));
typedef float f32x16 __attribute__((ext_vector_type(16)));
typedef float f32x2  __attribute__((ext_vector_type(2)));

#define NPTS 4096
#define BATCH 4
#define JCHUNK 512                 // 16 j-tiles of 32
#define LOG2E 1.4426950408889634f

// ---- 2048-block partition ----
#define NDIAG (2 * BATCH * 8 * 2)          // 128: 2 jobs per diag supertile
#define NOFF  (2 * BATCH * 28 * 4)         // 896: off-diag supertiles, 4 sub
#define NXY   (BATCH * 32 * 8)             // 1024
#define GRID_MAIN (NDIAG + NOFF + NXY)     // 2048 = 2 x 1024 slots exactly

// off-diagonal 8x8 supertile pairs: entry = (g<<4)|j5, g<j5 (28 entries)
__constant__ unsigned char OFF_TBL[28] = {
    0x01,0x02,0x03,0x04,0x05,0x06,0x07,
    0x12,0x13,0x14,0x15,0x16,0x17,
    0x23,0x24,0x25,0x26,0x27,
    0x34,0x35,0x36,0x37,
    0x45,0x46,0x47,
    0x56,0x57,
    0x67
};

static __device__ __forceinline__ short f2bf(float f) {
    unsigned u = __builtin_bit_cast(unsigned, f);
    unsigned r = u + 0x7fffu + ((u >> 16) & 1u);   // RNE
    return (short)(r >> 16);
}
// v -> h (exact bf16 value) + l (residual)
static __device__ __forceinline__ void split(float v, float& h, float& l) {
    unsigned u = __builtin_bit_cast(unsigned, v);
    unsigned rb = (u + 0x7fffu + ((u >> 16) & 1u)) & 0xffff0000u;
    h = __builtin_bit_cast(float, rb);
    l = v - h;
}

// slot pairing (A,B): (gh,1)(gl,1)(1,g'h)(1,g'l), per dim (uh,vh)(uh,vl)(ul,vh)
// u = 2*log2e*xi, v = xj, g = -log2e*|x|^2  => accS = -log2e * S_ij
static __device__ __forceinline__ void encodeA(float x0, float x1, float x2,
                                               float n0, float n1, float n2,
                                               float fS[16], float fD[16]) {
    float s2 = fmaf(x2, x2, fmaf(x1, x1, x0 * x0));
    float gh, gl; split(-LOG2E * s2, gh, gl);
    float u0h,u0l,u1h,u1l,u2h,u2l;
    split(2.f*LOG2E*x0, u0h, u0l);
    split(2.f*LOG2E*x1, u1h, u1l);
    split(2.f*LOG2E*x2, u2h, u2l);
    fS[0]=gh;  fS[1]=gl;  fS[2]=1.f; fS[3]=1.f;
    fS[4]=u0h; fS[5]=u0h; fS[6]=u0l;
    fS[7]=u1h; fS[8]=u1h; fS[9]=u1l;
    fS[10]=u2h; fS[11]=u2h; fS[12]=u2l;
    fS[13]=0.f; fS[14]=0.f; fS[15]=0.f;
    float m0h,m0l,m1h,m1l,m2h,m2l;
    split(n0, m0h, m0l); split(n1, m1h, m1l); split(n2, m2h, m2l);
    fD[0]=m0h; fD[1]=m0h; fD[2]=m0l;
    fD[3]=m1h; fD[4]=m1h; fD[5]=m1l;
    fD[6]=m2h; fD[7]=m2h; fD[8]=m2l;
#pragma unroll
    for (int k = 9; k < 16; ++k) fD[k] = 0.f;
}

static __device__ __forceinline__ void encodeB(float x0, float x1, float x2,
                                               float n0, float n1, float n2,
                                               float fS[16], float fD[16]) {
    float s2 = fmaf(x2, x2, fmaf(x1, x1, x0 * x0));
    float gh, gl; split(-LOG2E * s2, gh, gl);
    float v0h,v0l,v1h,v1l,v2h,v2l;
    split(x0, v0h, v0l); split(x1, v1h, v1l); split(x2, v2h, v2l);
    fS[0]=1.f; fS[1]=1.f; fS[2]=gh;  fS[3]=gl;
    fS[4]=v0h; fS[5]=v0l; fS[6]=v0h;
    fS[7]=v1h; fS[8]=v1l; fS[9]=v1h;
    fS[10]=v2h; fS[11]=v2l; fS[12]=v2h;
    fS[13]=0.f; fS[14]=0.f; fS[15]=0.f;
    float m0h,m0l,m1h,m1l,m2h,m2l;
    split(n0, m0h, m0l); split(n1, m1h, m1l); split(n2, m2h, m2l);
    fD[0]=m0h; fD[1]=m0l; fD[2]=m0h;
    fD[3]=m1h; fD[4]=m1l; fD[5]=m1h;
    fD[6]=m2h; fD[7]=m2l; fD[8]=m2h;
#pragma unroll
    for (int k = 9; k < 16; ++k) fD[k] = 0.f;
}

// f[16] -> two lane-major bf16x8 halves
static __device__ __forceinline__ void pack2(const float f[16], bf16x8& lo, bf16x8& hi) {
#pragma unroll
    for (int k = 0; k < 8; ++k) { lo[k] = f2bf(f[k]); hi[k] = f2bf(f[k + 8]); }
}

// packed degree-5 minimax exp2 on a pair (Mesa lp_build_exp2 coefficients,
// ~1e-7 rel on [0,1)): 8 scalar VALU + 5 v_pk_fma_f32 per pair.
static __device__ __forceinline__ f32x2 exp2_poly(f32x2 x) {
    const f32x2 C0 = {0.999999925f,   0.999999925f};
    const f32x2 C1 = {0.693153073f,   0.693153073f};
    const f32x2 C2 = {0.240153617f,   0.240153617f};
    const f32x2 C3 = {0.0558263180f,  0.0558263180f};
    const f32x2 C4 = {0.00898934009f, 0.00898934009f};
    const f32x2 C5 = {0.00187757667f, 0.00187757667f};
    float fl0 = floorf(x[0]);
    float fl1 = floorf(x[1]);
    f32x2 r; r[0] = x[0] - fl0; r[1] = x[1] - fl1;
    int n0 = (int)fl0, n1 = (int)fl1;
    f32x2 p = __builtin_elementwise_fma(C5, r, C4);
    p = __builtin_elementwise_fma(p, r, C3);
    p = __builtin_elementwise_fma(p, r, C2);
    p = __builtin_elementwise_fma(p, r, C1);
    p = __builtin_elementwise_fma(p, r, C0);
    f32x2 res;
    res[0] = ldexpf(p[0], n0);     // v_ldexp_f32
    res[1] = ldexpf(p[1], n1);
    return res;
}

// epilogue for one 32x32 tile: HYBRID -- values 0..7 via v_exp_f32 (trans),
// values 8..15 via packed polynomial (VALU). Accumulation order unchanged.
static __device__ __forceinline__ void epi(const f32x16& aS, const f32x16& aD,
                                           f32x2& q0, f32x2& q1) {
#pragma unroll
    for (int e = 0; e < 8; e += 4) {
        f32x2 ex0, ex1, d0, d1;
        ex0[0] = __builtin_amdgcn_exp2f(aS[e+0]);
        ex0[1] = __builtin_amdgcn_exp2f(aS[e+1]);
        ex1[0] = __builtin_amdgcn_exp2f(aS[e+2]);
        ex1[1] = __builtin_amdgcn_exp2f(aS[e+3]);
        d0[0] = aD[e+0]; d0[1] = aD[e+1];
        d1[0] = aD[e+2]; d1[1] = aD[e+3];
        q0 = __builtin_elementwise_fma(ex0 * d0, d0, q0);   // v_pk_mul + v_pk_fma
        q1 = __builtin_elementwise_fma(ex1 * d1, d1, q1);
    }
#pragma unroll
    for (int e = 8; e < 16; e += 4) {
        f32x2 x0, x1, d0, d1;
        x0[0] = aS[e+0]; x0[1] = aS[e+1];
        x1[0] = aS[e+2]; x1[1] = aS[e+3];
        f32x2 ex0 = exp2_poly(x0);
        f32x2 ex1 = exp2_poly(x1);
        d0[0] = aD[e+0]; d0[1] = aD[e+1];
        d1[0] = aD[e+2]; d1[1] = aD[e+3];
        q0 = __builtin_elementwise_fma(ex0 * d0, d0, q0);
        q1 = __builtin_elementwise_fma(ex1 * d1, d1, q1);
    }
}

__global__ __launch_bounds__(256, 4)   // 128 VGPR cap: room for VGPR-form accs
void vf_main(const float* __restrict__ xyz1, const float* __restrict__ xyz2,
             const float* __restrict__ nor1, const float* __restrict__ nor2,
             float* __restrict__ partials)
{
    __shared__ short sBS[JCHUNK * 16];   // 16 KB
    __shared__ short sBD[JCHUNK * 16];   // 16 KB

    int blk = blockIdx.x;
    const int tid  = threadIdx.x;
    const int lane = tid & 63;
    const int wv   = tid >> 6;

    // ---- decode block -> (kind, term, b, rows, jc) ----
    int term, b, jc;
    int isdiag = 0;
    int ib = 0;          // 128-row tile index (non-diag)
    int g = 0, job = 0;  // diag supertile + job
    float wgt = 0.f;     // folded weight for non-diag paths

    if (blk < NDIAG) {                       // diag supertiles, first (heavier)
        isdiag = 1;
        int d = blk;
        term = d >> 6; d &= 63;              // 0:xx 1:yy
        b = d & 3; d >>= 2;                  // 0..15
        g = d & 7; job = d >> 3;             // supertile, job 0/1
        jc = g;
    } else if (blk < NDIAG + NOFF) {         // off-diag supertiles, weight 2
        int o = blk - NDIAG;
        term = (o < NOFF / 2) ? 0 : 1;
        if (term) o -= NOFF / 2;
        b = o & 3; o >>= 2;                  // 0..111
        int sub = o & 3; int st = o >> 2;    // 0..27
        unsigned e = OFF_TBL[st];
        ib = (e >> 4) * 4 + sub;
        jc = e & 15;
        wgt = 2.f;
    } else {                                 // xy: full grid, weight -2
        int x = blk - (NDIAG + NOFF);
        term = 2;
        b = x & 3; x >>= 2;
        ib = x & 31;
        jc = x >> 5;                         // 0..7
        wgt = -2.f;
    }

    int sideA = (term == 1) ? 1 : 0;
    int sideB = (term == 0) ? 0 : 1;

    const float* pxA = (sideA ? xyz2 : xyz1) + (size_t)b * NPTS * 3;
    const float* pnA = (sideA ? nor2 : nor1) + (size_t)b * NPTS * 3;
    const float* pxB = (sideB ? xyz2 : xyz1) + (size_t)b * NPTS * 3;
    const float* pnB = (sideB ? nor2 : nor1) + (size_t)b * NPTS * 3;

    // ---- B chunk: encode 512 points straight into LDS (2 per thread),
    //      lane-major layout identical to the old fragment store ----
#pragma unroll
    for (int k = 0; k < 2; ++k) {
        int q = tid + k * 256;
        size_t off = (size_t)(jc * JCHUNK + q) * 3;
        float fS[16], fD[16];
        encodeB(pxB[off], pxB[off+1], pxB[off+2],
                pnB[off], pnB[off+1], pnB[off+2], fS, fD);
        bf16x8 slo, shi, dlo, dhi;
        pack2(fS, slo, shi);
        pack2(fD, dlo, dhi);
        int u = (q >> 5) * 64 + (q & 31);
        *(bf16x8*)&sBS[(size_t)u * 8]        = slo;
        *(bf16x8*)&sBS[((size_t)u + 32) * 8] = shi;
        *(bf16x8*)&sBD[(size_t)u * 8]        = dlo;
        *(bf16x8*)&sBD[((size_t)u + 32) * 8] = dhi;
    }

    const int hi = lane >> 5;   // which half of the 16-value encode this lane holds

    f32x16 z;
#pragma unroll
    for (int k = 0; k < 16; ++k) z[k] = 0.f;

    f32x2 q0 = {0.f, 0.f}, q1 = {0.f, 0.f};   // weight-2 (or block-wgt) accum
    f32x2 p0 = {0.f, 0.f}, p1 = {0.f, 0.f};   // weight-1 accum (diag tiles)
    float part;

    if (!isdiag) {
        // ---- A fragment: encode this wave's 32-row i-tile in-register ----
        int p = (ib * 4 + wv) * 32 + (lane & 31);
        size_t offA = (size_t)p * 3;
        float fS[16], fD[16];
        encodeA(pxA[offA], pxA[offA+1], pxA[offA+2],
                pnA[offA], pnA[offA+1], pnA[offA+2], fS, fD);
        bf16x8 slo, shi, dlo, dhi;
        pack2(fS, slo, shi);
        pack2(fD, dlo, dhi);
        bf16x8 AS, AD;
#pragma unroll
        for (int k = 0; k < 8; ++k) {
            AS[k] = hi ? shi[k] : slo[k];
            AD[k] = hi ? dhi[k] : dlo[k];
        }

        __syncthreads();

#pragma unroll
        for (int jt = 0; jt < JCHUNK / 32; ++jt) {
            int u = (jt * 64 + lane) * 8;
            bf16x8 BS = *(const bf16x8*)&sBS[u];
            bf16x8 BD = *(const bf16x8*)&sBD[u];
            f32x16 aSacc = __builtin_amdgcn_mfma_f32_32x32x16_bf16(AS, BS, z, 0, 0, 0);
            f32x16 aDacc = __builtin_amdgcn_mfma_f32_32x32x16_bf16(AD, BD, z, 0, 0, 0);
            epi(aSacc, aDacc, q0, q1);
        }
        part = wgt * ((q0[0] + q0[1]) + (q1[0] + q1[1]));
    } else {
        // ---- diag supertile job: wave covers row-tiles r and 15-r,
        //      j-tiles jt>=rt only; tile jt==rt weight 1, else weight 2 ----
        int r   = job * 4 + wv;              // 0..7
        int rt1 = r, rt2 = 15 - r;           // 17 tiles total per wave
        bf16x8 AS1, AD1, AS2, AD2;
        {
            int p = (g * 16 + rt1) * 32 + (lane & 31);
            size_t offA = (size_t)p * 3;
            float fS[16], fD[16];
            encodeA(pxA[offA], pxA[offA+1], pxA[offA+2],
                    pnA[offA], pnA[offA+1], pnA[offA+2], fS, fD);
            bf16x8 slo, shi, dlo, dhi;
            pack2(fS, slo, shi);
            pack2(fD, dlo, dhi);
#pragma unroll
            for (int k = 0; k < 8; ++k) {
                AS1[k] = hi ? shi[k] : slo[k];
                AD1[k] = hi ? dhi[k] : dlo[k];
            }
        }
        {
            int p = (g * 16 + rt2) * 32 + (lane & 31);
            size_t offA = (size_t)p * 3;
            float fS[16], fD[16];
            encodeA(pxA[offA], pxA[offA+1], pxA[offA+2],
                    pnA[offA], pnA[offA+1], pnA[offA+2], fS, fD);
            bf16x8 slo, shi, dlo, dhi;
            pack2(fS, slo, shi);
            pack2(fD, dlo, dhi);
#pragma unroll
            for (int k = 0; k < 8; ++k) {
                AS2[k] = hi ? shi[k] : slo[k];
                AD2[k] = hi ? dhi[k] : dlo[k];
            }
        }

        __syncthreads();

#pragma unroll
        for (int jt = 0; jt < JCHUNK / 32; ++jt) {
            int u = (jt * 64 + lane) * 8;
            bf16x8 BS = *(const bf16x8*)&sBS[u];
            bf16x8 BD = *(const bf16x8*)&sBD[u];
            if (jt >= rt1) {                 // wave-uniform branch
                f32x16 aS = __builtin_amdgcn_mfma_f32_32x32x16_bf16(AS1, BS, z, 0, 0, 0);
                f32x16 aD = __builtin_amdgcn_mfma_f32_32x32x16_bf16(AD1, BD, z, 0, 0, 0);
                if (jt == rt1) epi(aS, aD, p0, p1);
                else           epi(aS, aD, q0, q1);
            }
            if (jt >= rt2) {
                f32x16 aS = __builtin_amdgcn_mfma_f32_32x32x16_bf16(AS2, BS, z, 0, 0, 0);
                f32x16 aD = __builtin_amdgcn_mfma_f32_32x32x16_bf16(AD2, BD, z, 0, 0, 0);
                if (jt == rt2) epi(aS, aD, p0, p1);
                else           epi(aS, aD, q0, q1);
            }
        }
        part = ((p0[0] + p0[1]) + (p1[0] + p1[1]))
             + 2.f * ((q0[0] + q0[1]) + (q1[0] + q1[1]));
    }

#pragma unroll
    for (int off = 32; off > 0; off >>= 1)
        part += __shfl_down(part, off, 64);

    // Cross-wave reduce through 16 reused bytes of sBS (no extra LDS).
    __syncthreads();                       // all waves done reading LDS tiles
    float* red = (float*)sBS;
    if (lane == 0) red[wv] = part;
    __syncthreads();
    if (tid == 0) {
        float s = (red[0] + red[1]) + (red[2] + red[3]);
        partials[blk] = s;                 // plain store, distinct address
    }
}

__global__ __launch_bounds__(256)
void vf_reduce(const float* __restrict__ partials, float* __restrict__ out)
{
    int tid = threadIdx.x;
    double s = 0.0;
#pragma unroll
    for (int k = 0; k < (GRID_MAIN + 255) / 256; ++k) {
        int idx = tid + k * 256;
        if (idx < GRID_MAIN) s += (double)partials[idx];
    }
#pragma unroll
    for (int off = 32; off > 0; off >>= 1)
        s += __shfl_down(s, off, 64);
    __shared__ double red[4];
    int lane = tid & 63, wv = tid >> 6;
    if (lane == 0) red[wv] = s;
    __syncthreads();
    if (tid == 0)
        out[0] = (float)((red[0] + red[1]) + (red[2] + red[3]));
}

extern "C" void kernel_launch(void* const* d_in, const int* in_sizes, int n_in,
                              void* d_out, int out_size, void* d_ws, size_t ws_size,
                              hipStream_t stream) {
    const float* xyz1 = (const float*)d_in[0];
    const float* xyz2 = (const float*)d_in[1];
    const float* nor1 = (const float*)d_in[2];
    const float* nor2 = (const float*)d_in[3];
    float* out = (float*)d_out;
    float* partials = (float*)d_ws;    // 8KB: one float per block

    vf_main<<<GRID_MAIN, 256, 0, stream>>>(xyz1, xyz2, nor1, nor2, partials);
    vf_reduce<<<1, 256, 0, stream>>>(partials, out);
}

// Round 7
// 77.695 us; speedup vs baseline: 1.1100x; 1.1100x over previous
//
#include <hip/hip_runtime.h>

// Varifold loss kxx + kyy - 2*kxy via mfma_f32_32x32x16_bf16, two-phase.
// R17 = exact revert to R15 (best measured: 77.7us). R16's hybrid
// trans/VALU exp2 regressed (77.7->86.2): replacing 8 of 16 v_exp_f32
// with a packed degree-5 polynomial ADDED ~104 VALU issue-cyc/tile and
// slowed vf_main ~35%. LESSON (model corrected): v_exp_f32 issues in a
// few cycles and retires in the background trans pipe -- it does NOT
// block issue ~16cyc. The inner loop is VALU-ISSUE-bound (MFMA issue +
// pk_mul/pk_fma + ds_read + loop overhead); exps are mostly hidden.
// Never move trans work onto the VALU in this kernel.
//
// R15 (kept): encode fused into vf_main. Each block re-encodes its own
// A-points (in-register) and 512 B-points (straight into LDS, lane-major)
// from raw inputs (786KB, L2-resident). Workspace = 8KB partials.
// Measured: 81.6 -> 77.7us.
// R14 (kept): grid = EXACTLY 2048 near-uniform blocks (2 x 1024 slots;
// 4 blocks/CU x 256 CU). Diagonal supertiles compute upper-triangle TILES
// only (diag tile wgt 1, off-diag 2; row r paired with 15-r -> 8 uniform
// 17-tile wave-jobs). Measured: 86.7 -> 81.6us.
//
// vf_main: lane-major fragments -> conflict-free ds_read_b128. Builtin
// MFMA (R7: raw-asm -> hazard corruption). No same-address atomics (R5).
// Per-block plain store of partial. vf_reduce: one block double-sums
// 2048 partials -> out[0].
//
// Failed levers (do not retry):
// - Hybrid/poly exp2 epilogue (R16, +8.5us): kernel is VALU-issue-bound;
//   v_exp_f32 is nearly free (trans pipe), poly VALU is not.
// - Fused last-block reduce via __threadfence + atomic counter (R11/R12):
//   device-scope fence emits buffer_wbl2/buffer_inv sc1 per block -> L2
//   writebacks AND invalidation of the L2-resident working set all
//   concurrent blocks re-read -> latency-bound, vf_main 27->66.7us.
//   NEVER device-fence a kernel relying on L2-resident reuse.
// - Direct-global B reads + depth-1 prefetch, no LDS (R11): cross-XCD L3
//   hits ~500-900cyc, L1 thrashes, vf_main 27->58.6us.
// - Packed-f32 epilogue (R8, ~0), 8 blocks/CU occupancy (R8, ~0), VGPR cap
//   below 128 (R9, -1.5us), SW pipeline depth 1 on MFMA (R10, +2us),
//   inline-asm MFMA (R7, corrupt).

typedef short bf16x8 __attribute__((ext_vector_type(8)));
typedef float f32x16 __attribute__((ext_vector_type(16)));
typedef float f32x2  __attribute__((ext_vector_type(2)));

#define NPTS 4096
#define BATCH 4
#define JCHUNK 512                 // 16 j-tiles of 32
#define LOG2E 1.4426950408889634f

// ---- 2048-block partition ----
#define NDIAG (2 * BATCH * 8 * 2)          // 128: 2 jobs per diag supertile
#define NOFF  (2 * BATCH * 28 * 4)         // 896: off-diag supertiles, 4 sub
#define NXY   (BATCH * 32 * 8)             // 1024
#define GRID_MAIN (NDIAG + NOFF + NXY)     // 2048 = 2 x 1024 slots exactly

// off-diagonal 8x8 supertile pairs: entry = (g<<4)|j5, g<j5 (28 entries)
__constant__ unsigned char OFF_TBL[28] = {
    0x01,0x02,0x03,0x04,0x05,0x06,0x07,
    0x12,0x13,0x14,0x15,0x16,0x17,
    0x23,0x24,0x25,0x26,0x27,
    0x34,0x35,0x36,0x37,
    0x45,0x46,0x47,
    0x56,0x57,
    0x67
};

static __device__ __forceinline__ short f2bf(float f) {
    unsigned u = __builtin_bit_cast(unsigned, f);
    unsigned r = u + 0x7fffu + ((u >> 16) & 1u);   // RNE
    return (short)(r >> 16);
}
// v -> h (exact bf16 value) + l (residual)
static __device__ __forceinline__ void split(float v, float& h, float& l) {
    unsigned u = __builtin_bit_cast(unsigned, v);
    unsigned rb = (u + 0x7fffu + ((u >> 16) & 1u)) & 0xffff0000u;
    h = __builtin_bit_cast(float, rb);
    l = v - h;
}

// slot pairing (A,B): (gh,1)(gl,1)(1,g'h)(1,g'l), per dim (uh,vh)(uh,vl)(ul,vh)
// u = 2*log2e*xi, v = xj, g = -log2e*|x|^2  => accS = -log2e * S_ij
static __device__ __forceinline__ void encodeA(float x0, float x1, float x2,
                                               float n0, float n1, float n2,
                                               float fS[16], float fD[16]) {
    float s2 = fmaf(x2, x2, fmaf(x1, x1, x0 * x0));
    float gh, gl; split(-LOG2E * s2, gh, gl);
    float u0h,u0l,u1h,u1l,u2h,u2l;
    split(2.f*LOG2E*x0, u0h, u0l);
    split(2.f*LOG2E*x1, u1h, u1l);
    split(2.f*LOG2E*x2, u2h, u2l);
    fS[0]=gh;  fS[1]=gl;  fS[2]=1.f; fS[3]=1.f;
    fS[4]=u0h; fS[5]=u0h; fS[6]=u0l;
    fS[7]=u1h; fS[8]=u1h; fS[9]=u1l;
    fS[10]=u2h; fS[11]=u2h; fS[12]=u2l;
    fS[13]=0.f; fS[14]=0.f; fS[15]=0.f;
    float m0h,m0l,m1h,m1l,m2h,m2l;
    split(n0, m0h, m0l); split(n1, m1h, m1l); split(n2, m2h, m2l);
    fD[0]=m0h; fD[1]=m0h; fD[2]=m0l;
    fD[3]=m1h; fD[4]=m1h; fD[5]=m1l;
    fD[6]=m2h; fD[7]=m2h; fD[8]=m2l;
#pragma unroll
    for (int k = 9; k < 16; ++k) fD[k] = 0.f;
}

static __device__ __forceinline__ void encodeB(float x0, float x1, float x2,
                                               float n0, float n1, float n2,
                                               float fS[16], float fD[16]) {
    float s2 = fmaf(x2, x2, fmaf(x1, x1, x0 * x0));
    float gh, gl; split(-LOG2E * s2, gh, gl);
    float v0h,v0l,v1h,v1l,v2h,v2l;
    split(x0, v0h, v0l); split(x1, v1h, v1l); split(x2, v2h, v2l);
    fS[0]=1.f; fS[1]=1.f; fS[2]=gh;  fS[3]=gl;
    fS[4]=v0h; fS[5]=v0l; fS[6]=v0h;
    fS[7]=v1h; fS[8]=v1l; fS[9]=v1h;
    fS[10]=v2h; fS[11]=v2l; fS[12]=v2h;
    fS[13]=0.f; fS[14]=0.f; fS[15]=0.f;
    float m0h,m0l,m1h,m1l,m2h,m2l;
    split(n0, m0h, m0l); split(n1, m1h, m1l); split(n2, m2h, m2l);
    fD[0]=m0h; fD[1]=m0l; fD[2]=m0h;
    fD[3]=m1h; fD[4]=m1l; fD[5]=m1h;
    fD[6]=m2h; fD[7]=m2l; fD[8]=m2h;
#pragma unroll
    for (int k = 9; k < 16; ++k) fD[k] = 0.f;
}

// f[16] -> two lane-major bf16x8 halves
static __device__ __forceinline__ void pack2(const float f[16], bf16x8& lo, bf16x8& hi) {
#pragma unroll
    for (int k = 0; k < 8; ++k) { lo[k] = f2bf(f[k]); hi[k] = f2bf(f[k + 8]); }
}

// epilogue for one 32x32 tile: 16 exp2 (trans) + packed mul/fma (VOP3P)
static __device__ __forceinline__ void epi(const f32x16& aS, const f32x16& aD,
                                           f32x2& q0, f32x2& q1) {
#pragma unroll
    for (int e = 0; e < 16; e += 4) {
        f32x2 ex0, ex1, d0, d1;
        ex0[0] = __builtin_amdgcn_exp2f(aS[e+0]);
        ex0[1] = __builtin_amdgcn_exp2f(aS[e+1]);
        ex1[0] = __builtin_amdgcn_exp2f(aS[e+2]);
        ex1[1] = __builtin_amdgcn_exp2f(aS[e+3]);
        d0[0] = aD[e+0]; d0[1] = aD[e+1];
        d1[0] = aD[e+2]; d1[1] = aD[e+3];
        q0 = __builtin_elementwise_fma(ex0 * d0, d0, q0);   // v_pk_mul + v_pk_fma
        q1 = __builtin_elementwise_fma(ex1 * d1, d1, q1);
    }
}

__global__ __launch_bounds__(256, 4)   // 128 VGPR cap: room for VGPR-form accs
void vf_main(const float* __restrict__ xyz1, const float* __restrict__ xyz2,
             const float* __restrict__ nor1, const float* __restrict__ nor2,
             float* __restrict__ partials)
{
    __shared__ short sBS[JCHUNK * 16];   // 16 KB
    __shared__ short sBD[JCHUNK * 16];   // 16 KB

    int blk = blockIdx.x;
    const int tid  = threadIdx.x;
    const int lane = tid & 63;
    const int wv   = tid >> 6;

    // ---- decode block -> (kind, term, b, rows, jc) ----
    int term, b, jc;
    int isdiag = 0;
    int ib = 0;          // 128-row tile index (non-diag)
    int g = 0, job = 0;  // diag supertile + job
    float wgt = 0.f;     // folded weight for non-diag paths

    if (blk < NDIAG) {                       // diag supertiles, first (heavier)
        isdiag = 1;
        int d = blk;
        term = d >> 6; d &= 63;              // 0:xx 1:yy
        b = d & 3; d >>= 2;                  // 0..15
        g = d & 7; job = d >> 3;             // supertile, job 0/1
        jc = g;
    } else if (blk < NDIAG + NOFF) {         // off-diag supertiles, weight 2
        int o = blk - NDIAG;
        term = (o < NOFF / 2) ? 0 : 1;
        if (term) o -= NOFF / 2;
        b = o & 3; o >>= 2;                  // 0..111
        int sub = o & 3; int st = o >> 2;    // 0..27
        unsigned e = OFF_TBL[st];
        ib = (e >> 4) * 4 + sub;
        jc = e & 15;
        wgt = 2.f;
    } else {                                 // xy: full grid, weight -2
        int x = blk - (NDIAG + NOFF);
        term = 2;
        b = x & 3; x >>= 2;
        ib = x & 31;
        jc = x >> 5;                         // 0..7
        wgt = -2.f;
    }

    int sideA = (term == 1) ? 1 : 0;
    int sideB = (term == 0) ? 0 : 1;

    const float* pxA = (sideA ? xyz2 : xyz1) + (size_t)b * NPTS * 3;
    const float* pnA = (sideA ? nor2 : nor1) + (size_t)b * NPTS * 3;
    const float* pxB = (sideB ? xyz2 : xyz1) + (size_t)b * NPTS * 3;
    const float* pnB = (sideB ? nor2 : nor1) + (size_t)b * NPTS * 3;

    // ---- B chunk: encode 512 points straight into LDS (2 per thread),
    //      lane-major layout identical to the old fragment store ----
#pragma unroll
    for (int k = 0; k < 2; ++k) {
        int q = tid + k * 256;
        size_t off = (size_t)(jc * JCHUNK + q) * 3;
        float fS[16], fD[16];
        encodeB(pxB[off], pxB[off+1], pxB[off+2],
                pnB[off], pnB[off+1], pnB[off+2], fS, fD);
        bf16x8 slo, shi, dlo, dhi;
        pack2(fS, slo, shi);
        pack2(fD, dlo, dhi);
        int u = (q >> 5) * 64 + (q & 31);
        *(bf16x8*)&sBS[(size_t)u * 8]        = slo;
        *(bf16x8*)&sBS[((size_t)u + 32) * 8] = shi;
        *(bf16x8*)&sBD[(size_t)u * 8]        = dlo;
        *(bf16x8*)&sBD[((size_t)u + 32) * 8] = dhi;
    }

    const int hi = lane >> 5;   // which half of the 16-value encode this lane holds

    f32x16 z;
#pragma unroll
    for (int k = 0; k < 16; ++k) z[k] = 0.f;

    f32x2 q0 = {0.f, 0.f}, q1 = {0.f, 0.f};   // weight-2 (or block-wgt) accum
    f32x2 p0 = {0.f, 0.f}, p1 = {0.f, 0.f};   // weight-1 accum (diag tiles)
    float part;

    if (!isdiag) {
        // ---- A fragment: encode this wave's 32-row i-tile in-register ----
        int p = (ib * 4 + wv) * 32 + (lane & 31);
        size_t offA = (size_t)p * 3;
        float fS[16], fD[16];
        encodeA(pxA[offA], pxA[offA+1], pxA[offA+2],
                pnA[offA], pnA[offA+1], pnA[offA+2], fS, fD);
        bf16x8 slo, shi, dlo, dhi;
        pack2(fS, slo, shi);
        pack2(fD, dlo, dhi);
        bf16x8 AS, AD;
#pragma unroll
        for (int k = 0; k < 8; ++k) {
            AS[k] = hi ? shi[k] : slo[k];
            AD[k] = hi ? dhi[k] : dlo[k];
        }

        __syncthreads();

#pragma unroll
        for (int jt = 0; jt < JCHUNK / 32; ++jt) {
            int u = (jt * 64 + lane) * 8;
            bf16x8 BS = *(const bf16x8*)&sBS[u];
            bf16x8 BD = *(const bf16x8*)&sBD[u];
            f32x16 aSacc = __builtin_amdgcn_mfma_f32_32x32x16_bf16(AS, BS, z, 0, 0, 0);
            f32x16 aDacc = __builtin_amdgcn_mfma_f32_32x32x16_bf16(AD, BD, z, 0, 0, 0);
            epi(aSacc, aDacc, q0, q1);
        }
        part = wgt * ((q0[0] + q0[1]) + (q1[0] + q1[1]));
    } else {
        // ---- diag supertile job: wave covers row-tiles r and 15-r,
        //      j-tiles jt>=rt only; tile jt==rt weight 1, else weight 2 ----
        int r   = job * 4 + wv;              // 0..7
        int rt1 = r, rt2 = 15 - r;           // 17 tiles total per wave
        bf16x8 AS1, AD1, AS2, AD2;
        {
            int p = (g * 16 + rt1) * 32 + (lane & 31);
            size_t offA = (size_t)p * 3;
            float fS[16], fD[16];
            encodeA(pxA[offA], pxA[offA+1], pxA[offA+2],
                    pnA[offA], pnA[offA+1], pnA[offA+2], fS, fD);
            bf16x8 slo, shi, dlo, dhi;
            pack2(fS, slo, shi);
            pack2(fD, dlo, dhi);
#pragma unroll
            for (int k = 0; k < 8; ++k) {
                AS1[k] = hi ? shi[k] : slo[k];
                AD1[k] = hi ? dhi[k] : dlo[k];
            }
        }
        {
            int p = (g * 16 + rt2) * 32 + (lane & 31);
            size_t offA = (size_t)p * 3;
            float fS[16], fD[16];
            encodeA(pxA[offA], pxA[offA+1], pxA[offA+2],
                    pnA[offA], pnA[offA+1], pnA[offA+2], fS, fD);
            bf16x8 slo, shi, dlo, dhi;
            pack2(fS, slo, shi);
            pack2(fD, dlo, dhi);
#pragma unroll
            for (int k = 0; k < 8; ++k) {
                AS2[k] = hi ? shi[k] : slo[k];
                AD2[k] = hi ? dhi[k] : dlo[k];
            }
        }

        __syncthreads();

#pragma unroll
        for (int jt = 0; jt < JCHUNK / 32; ++jt) {
            int u = (jt * 64 + lane) * 8;
            bf16x8 BS = *(const bf16x8*)&sBS[u];
            bf16x8 BD = *(const bf16x8*)&sBD[u];
            if (jt >= rt1) {                 // wave-uniform branch
                f32x16 aS = __builtin_amdgcn_mfma_f32_32x32x16_bf16(AS1, BS, z, 0, 0, 0);
                f32x16 aD = __builtin_amdgcn_mfma_f32_32x32x16_bf16(AD1, BD, z, 0, 0, 0);
                if (jt == rt1) epi(aS, aD, p0, p1);
                else           epi(aS, aD, q0, q1);
            }
            if (jt >= rt2) {
                f32x16 aS = __builtin_amdgcn_mfma_f32_32x32x16_bf16(AS2, BS, z, 0, 0, 0);
                f32x16 aD = __builtin_amdgcn_mfma_f32_32x32x16_bf16(AD2, BD, z, 0, 0, 0);
                if (jt == rt2) epi(aS, aD, p0, p1);
                else           epi(aS, aD, q0, q1);
            }
        }
        part = ((p0[0] + p0[1]) + (p1[0] + p1[1]))
             + 2.f * ((q0[0] + q0[1]) + (q1[0] + q1[1]));
    }

#pragma unroll
    for (int off = 32; off > 0; off >>= 1)
        part += __shfl_down(part, off, 64);

    // Cross-wave reduce through 16 reused bytes of sBS (no extra LDS).
    __syncthreads();                       // all waves done reading LDS tiles
    float* red = (float*)sBS;
    if (lane == 0) red[wv] = part;
    __syncthreads();
    if (tid == 0) {
        float s = (red[0] + red[1]) + (red[2] + red[3]);
        partials[blk] = s;                 // plain store, distinct address
    }
}

__global__ __launch_bounds__(256)
void vf_reduce(const float* __restrict__ partials, float* __restrict__ out)
{
    int tid = threadIdx.x;
    double s = 0.0;
#pragma unroll
    for (int k = 0; k < (GRID_MAIN + 255) / 256; ++k) {
        int idx = tid + k * 256;
        if (idx < GRID_MAIN) s += (double)partials[idx];
    }
#pragma unroll
    for (int off = 32; off > 0; off >>= 1)
        s += __shfl_down(s, off, 64);
    __shared__ double red[4];
    int lane = tid & 63, wv = tid >> 6;
    if (lane == 0) red[wv] = s;
    __syncthreads();
    if (tid == 0)
        out[0] = (float)((red[0] + red[1]) + (red[2] + red[3]));
}

extern "C" void kernel_launch(void* const* d_in, const int* in_sizes, int n_in,
                              void* d_out, int out_size, void* d_ws, size_t ws_size,
                              hipStream_t stream) {
    const float* xyz1 = (const float*)d_in[0];
    const float* xyz2 = (const float*)d_in[1];
    const float* nor1 = (const float*)d_in[2];
    const float* nor2 = (const float*)d_in[3];
    float* out = (float*)d_out;
    float* partials = (float*)d_ws;    // 8KB: one float per block

    vf_main<<<GRID_MAIN, 256, 0, stream>>>(xyz1, xyz2, nor1, nor2, partials);
    vf_reduce<<<1, 256, 0, stream>>>(partials, out);
}